// Round 10
// baseline (127.144 us; speedup 1.0000x reference)
//
#include <hip/hip_runtime.h>
#include <hip/hip_bf16.h>

#define EDIM 256
#define NROWS 8192
#define GRIDX 4                    // 2048-col chunks
#define GRIDY 128                  // 64-row chunks
#define NBLOCKS (GRIDX * GRIDY)    // 512 = 2 blocks/CU
#define ITERS 32                   // 2048 / 64 cols per tile

typedef __attribute__((ext_vector_type(8))) short bf16x8;
typedef __attribute__((ext_vector_type(4))) float f32x4;

__device__ __forceinline__ unsigned short f2bf(float f) {
  unsigned int u = __float_as_uint(f);
  unsigned int r = (u + 0x7fffu + ((u >> 16) & 1u)) >> 16;  // RNE
  return (unsigned short)r;
}

__device__ __forceinline__ void gload_lds16(const void* g, void* l) {
  __builtin_amdgcn_global_load_lds(
      (const __attribute__((address_space(1))) unsigned int*)g,
      (__attribute__((address_space(3))) unsigned int*)l, 16, 0, 0);
}

// ---------------------------------------------------------------------------
// Kernel 1: normalize + transpose -> bf16 W[8192][256]; zero done counter.
// ---------------------------------------------------------------------------
__global__ __launch_bounds__(256) void detcon_normalize(
    const float* __restrict__ v0, const float* __restrict__ v1,
    __hip_bfloat16* __restrict__ Wb, unsigned int* __restrict__ done) {
  __shared__ float Xs[EDIM][32];
  __shared__ float part[4][32];
  __shared__ float scale_s[32];
  const int t = threadIdx.x;
  const int bid = blockIdx.x;              // 0..255
  if (bid == 0 && t == 0) *done = 0u;
  const int view = bid >> 7;
  const int b = (bid >> 1) & 63;
  const int nh = (bid & 1) * 32;
  const float* src = (view ? v1 : v0) + (size_t)b * (EDIM * 64);

  const int n4 = t & 7;
  const int eg = t >> 3;
  float4 ss = {0.f, 0.f, 0.f, 0.f};
#pragma unroll
  for (int i = 0; i < 8; ++i) {
    const int e = i * 32 + eg;
    float4 x = *(const float4*)(src + e * 64 + nh + n4 * 4);
    *(float4*)(&Xs[e][n4 * 4]) = x;
    ss.x += x.x * x.x; ss.y += x.y * x.y; ss.z += x.z * x.z; ss.w += x.w * x.w;
  }
#pragma unroll
  for (int m = 8; m <= 32; m <<= 1) {
    ss.x += __shfl_xor(ss.x, m, 64);
    ss.y += __shfl_xor(ss.y, m, 64);
    ss.z += __shfl_xor(ss.z, m, 64);
    ss.w += __shfl_xor(ss.w, m, 64);
  }
  if ((t & 63) < 8) *(float4*)(&part[t >> 6][(t & 7) * 4]) = ss;
  __syncthreads();
  if (t < 32) {
    const float total = part[0][t] + part[1][t] + part[2][t] + part[3][t];
    scale_s[t] = 3.16227766016838f / (sqrtf(total) + 1e-8f);
  }
  __syncthreads();

  const int nl = t >> 3;
  const int e0 = (t & 7) * 32;
  const float sc = scale_s[nl];
  const size_t r = (size_t)view * 4096 + (size_t)b * 64 + nh + nl;
  __hip_bfloat16* dst = Wb + r * EDIM;
#pragma unroll
  for (int j = 0; j < 4; ++j) {
    bf16x8 o;
#pragma unroll
    for (int u = 0; u < 8; ++u)
      o[u] = (short)f2bf(Xs[e0 + j * 8 + u][nl] * sc);
    *(bf16x8*)(dst + e0 + j * 8) = o;
  }
}

// ---------------------------------------------------------------------------
// Kernel 2: fused Gram + sum-of-exp. Grid (4,128) = 512 blocks = 2/CU.
// Block = 64 rows x 2048 cols, 256 thr = 4 waves, each wave a 16-col strip.
// Wave engine = R2-proven: a[4][8] full-K in regs, 1 swizzled ds_read_b128
// per kb (reads/MFMA = 0.25), 64-col double-buffered tiles, 1 barrier/iter.
// NO launch_bounds min-waves (R9 spill lesson). Two co-resident blocks give
// cross-block MFMA/stage-drain overlap on every SIMD.
// Atomic-free: LDS cross-wave row reduce -> Spart[GRIDX][row] plain stores.
// In-loop sd/pd extraction; done-counter finalize (2 graph nodes total).
// ---------------------------------------------------------------------------
__global__ __launch_bounds__(256) void detcon_gram(
    const __hip_bfloat16* __restrict__ Wbh, float* __restrict__ Spart,
    float* __restrict__ sd, float* __restrict__ pd,
    unsigned int* __restrict__ done, float* __restrict__ out) {
  __shared__ __align__(16) unsigned char b_lds[2][32768];
  __shared__ float rowacc[4][64];
  __shared__ float red[4];
  __shared__ int lastFlag;
  const int tid = threadIdx.x;             // 0..255
  const int lane = tid & 63;
  const int wid = tid >> 6;                // 0..3 = wave's 16-col strip
  const int rowbase = blockIdx.y * 64;
  const int colblock = blockIdx.x * 2048;
  const unsigned short* W = (const unsigned short*)Wbh;
  const char* Wbytes = (const char*)Wbh;

  // A fragments, full K: lane holds A[rowbase+m*16+(lane&15)][kb*32+(lane>>4)*8 ..+8]
  bf16x8 a[4][8];
#pragma unroll
  for (int m = 0; m < 4; ++m) {
    const unsigned row = rowbase + m * 16 + (lane & 15);
#pragma unroll
    for (int kb = 0; kb < 8; ++kb)
      a[m][kb] = *(const bf16x8*)(W + (row << 8) + kb * 32 + (lane >> 4) * 8);
  }

  f32x4 acc[4];
  float s[4][4];
#pragma unroll
  for (int m = 0; m < 4; ++m) {
    acc[m] = (f32x4){0.f, 0.f, 0.f, 0.f};
#pragma unroll
    for (int j = 0; j < 4; ++j) s[m][j] = 0.f;
  }

  // Stage 64 cols x 512 B (32 KB) with 256 threads: 8 rounds of 16 B each.
  // LDS dest linear (q = i*4096 + tid*16); source pre-swizzled (involution).
  const int stage_cl = (tid >> 5);          // + i*8
  const int stage_inner = (tid & 31) * 16;

#define STAGE(BUF, CB)                                                         \
  {                                                                            \
    _Pragma("unroll")                                                          \
    for (int i = 0; i < 8; ++i) {                                              \
      const int cl = i * 8 + stage_cl;                                         \
      const char* g = Wbytes + ((size_t)((CB) + cl) << 9) +                    \
                      (stage_inner ^ ((cl & 7) << 4));                         \
      gload_lds16(g, &b_lds[BUF][i * 4096 + tid * 16]);                        \
    }                                                                          \
  }

  STAGE(0, colblock);
  __syncthreads();

  const int jl = (lane & 15) - ((lane >> 4) << 2);
  int cur = 0;
  for (int it = 0; it < ITERS; ++it) {
    if (it < ITERS - 1) STAGE(cur ^ 1, colblock + (it + 1) * 64);

    // ---- compute: wave = 64 rows x 16 cols, 32 MFMA ----
    const int cl = wid * 16 + (lane & 15);
    const unsigned char* bbase = &b_lds[cur][0] + ((unsigned)cl << 9);
    const int csw = (cl & 7) << 4;
#pragma unroll
    for (int kb = 0; kb < 8; ++kb) {
      bf16x8 bfrag =
          *(const bf16x8*)(bbase + ((kb * 64 + (lane >> 4) * 16) ^ csw));
#pragma unroll
      for (int m = 0; m < 4; ++m)
        acc[m] = __builtin_amdgcn_mfma_f32_16x16x32_bf16(a[m][kb], bfrag,
                                                         acc[m], 0, 0, 0);
    }

    // ---- rare wave-uniform extraction of diag / positive logits ----
    const int strip0 = colblock + it * 64 + wid * 16;
    const unsigned d0 = (unsigned)(strip0 - rowbase);
    if (d0 < 64u) {
      const int dm = (int)(d0 >> 4);
#pragma unroll
      for (int m = 0; m < 4; ++m)
        if (m == dm) {
#pragma unroll
          for (int j = 0; j < 4; ++j)
            if (j == jl) sd[strip0 + (lane & 15)] = acc[m][j];
        }
    }
    const unsigned p0 = (unsigned)(((strip0 + 4096) & 8191) - rowbase);
    if (p0 < 64u) {
      const int pm = (int)(p0 >> 4);
#pragma unroll
      for (int m = 0; m < 4; ++m)
        if (m == pm) {
#pragma unroll
          for (int j = 0; j < 4; ++j)
            if (j == jl) pd[(strip0 + (lane & 15) + 4096) & 8191] = acc[m][j];
        }
    }

    // ---- exp-accumulate (diag included; removed in finalize) ----
#pragma unroll
    for (int m = 0; m < 4; ++m) {
#pragma unroll
      for (int j = 0; j < 4; ++j) s[m][j] += __expf(acc[m][j]);
      acc[m] = (f32x4){0.f, 0.f, 0.f, 0.f};
    }
    __syncthreads();   // drains next-tile stage (issued a full phase ago)
    cur ^= 1;
  }

  // ---- per-row sums: 16-lane shuffle reduce -> LDS cross-wave -> Spart ----
#pragma unroll
  for (int m = 0; m < 4; ++m) {
#pragma unroll
    for (int j = 0; j < 4; ++j) {
      float v = s[m][j];
      v += __shfl_xor(v, 1, 64);
      v += __shfl_xor(v, 2, 64);
      v += __shfl_xor(v, 4, 64);
      v += __shfl_xor(v, 8, 64);
      if ((lane & 15) == 0)
        rowacc[wid][m * 16 + (lane >> 4) * 4 + j] = v;
    }
  }
  __syncthreads();
  if (tid < 64)
    Spart[(size_t)blockIdx.x * NROWS + rowbase + tid] =
        rowacc[0][tid] + rowacc[1][tid] + rowacc[2][tid] + rowacc[3][tid];

  // ---- grid completion: last block finalizes ----
  __syncthreads();
  if (tid == 0) {
    __threadfence();
    lastFlag = (atomicAdd(done, 1u) == (unsigned)(NBLOCKS - 1));
  }
  __syncthreads();
  if (lastFlag) {
    __threadfence();
    float local = 0.f;
    for (int r = tid; r < NROWS; r += 256) {
      const float Ssum = Spart[r] + Spart[NROWS + r] + Spart[2 * NROWS + r] +
                         Spart[3 * NROWS + r];
      local += logf(Ssum - __expf(sd[r])) - pd[r];
    }
#pragma unroll
    for (int m = 32; m >= 1; m >>= 1) local += __shfl_xor(local, m, 64);
    if ((tid & 63) == 0) red[tid >> 6] = local;
    __syncthreads();
    if (tid == 0)
      out[0] = (red[0] + red[1] + red[2] + red[3]) * (1.0f / (float)NROWS);
  }
#undef STAGE
}

extern "C" void kernel_launch(void* const* d_in, const int* in_sizes, int n_in,
                              void* d_out, int out_size, void* d_ws, size_t ws_size,
                              hipStream_t stream) {
  const float* v0 = (const float*)d_in[0];
  const float* v1 = (const float*)d_in[1];
  float* out = (float*)d_out;

  // ws: Wb bf16[8192][256] | Spart f32[4][8192] | sd f32[8192] | pd f32[8192] | done
  __hip_bfloat16* Wb = (__hip_bfloat16*)d_ws;
  char* base = (char*)d_ws + (size_t)NROWS * EDIM * 2;
  float* Spart = (float*)base;
  float* sd = Spart + (size_t)GRIDX * NROWS;
  float* pd = sd + NROWS;
  unsigned int* done = (unsigned int*)(pd + NROWS);

  detcon_normalize<<<256, 256, 0, stream>>>(v0, v1, Wb, done);
  detcon_gram<<<dim3(GRIDX, GRIDY), 256, 0, stream>>>(Wb, Spart, sd, pd, done,
                                                      out);
}